// Round 6
// baseline (24785.909 us; speedup 1.0000x reference)
//
#include <hip/hip_runtime.h>

#define TDS 512
#define NBATCH 256

// f16 pair pack/unpack (RNE)
__device__ __forceinline__ unsigned int pk2_rne(float lo, float hi) {
    union { __fp16 h[2]; unsigned int i; } v;
    v.h[0] = (__fp16)lo; v.h[1] = (__fp16)hi;
    return v.i;
}
__device__ __forceinline__ float flo(unsigned int u) {
    union { unsigned int i; __fp16 h[2]; } v; v.i = u; return (float)v.h[0];
}
__device__ __forceinline__ float fhi(unsigned int u) {
    union { unsigned int i; __fp16 h[2]; } v; v.i = u; return (float)v.h[1];
}

// Output element offsets (float32 elements)
#define KEYS_OFF 0u
#define PRS_OFF  262144u
#define HS_OFF   786432u
#define TM_OFF   67895296u

__device__ __forceinline__ void flush_window(
    float* __restrict__ g_out, int b, int tid, int w,
    const float* __restrict__ lds_hst,
    const float (*__restrict__ lds_kst)[2],
    const float (*__restrict__ lds_pst)[4])
{
    const int tbase = w * 8;
    float h[8];
#pragma unroll
    for (int s = 0; s < 8; ++s) h[s] = lds_hst[s * TDS + tid];
    float4* dst = (float4*)(g_out + HS_OFF + (unsigned)b * 262144u + (unsigned)tid * 512u + (unsigned)tbase);
    dst[0] = make_float4(h[0], h[1], h[2], h[3]);
    dst[1] = make_float4(h[4], h[5], h[6], h[7]);

    if (tid < 2) {
        float k[8];
#pragma unroll
        for (int s = 0; s < 8; ++s) k[s] = lds_kst[s][tid];
        float4* kd = (float4*)(g_out + KEYS_OFF + (unsigned)b * 1024u + (unsigned)tid * 512u + (unsigned)tbase);
        kd[0] = make_float4(k[0], k[1], k[2], k[3]);
        kd[1] = make_float4(k[4], k[5], k[6], k[7]);
    } else if (tid < 6) {
        const int o = tid - 2;
        float p[8];
#pragma unroll
        for (int s = 0; s < 8; ++s) p[s] = lds_pst[s][o];
        float4* pd = (float4*)(g_out + PRS_OFF + (unsigned)b * 2048u + (unsigned)o * 512u + (unsigned)tbase);
        pd[0] = make_float4(p[0], p[1], p[2], p[3]);
        pd[1] = make_float4(p[4], p[5], p[6], p[7]);
    }
}

__global__ __launch_bounds__(TDS, 1) void rnn_att_kernel(
    const float* __restrict__ g_inputs,  // (256, 8, 512) f32
    const float* __restrict__ g_Win,     // (512, 6)
    const float* __restrict__ g_bin,     // (512,)
    const float* __restrict__ g_Wrec,    // (512, 512)
    const float* __restrict__ g_brec,    // (512,)
    const float* __restrict__ g_Wkey,    // (2, 512)
    const float* __restrict__ g_bkey,    // (2,)
    float* __restrict__ g_out)
{
    // LDS: 128K weight tier + 4K h dbuf + 16K staging + small ≈ 148.5 KB
    __shared__ __attribute__((aligned(16))) unsigned int lds_w[64][TDS];   // f16-pair weight tier
    __shared__ __attribute__((aligned(16))) float lds_hf[2 * TDS];         // f32 h double buffer
    __shared__ __attribute__((aligned(16))) float lds_hst[8 * TDS];        // hs staging [s][row]
    __shared__ float lds_ksum[2][16];
    __shared__ float lds_kst[8][2];
    __shared__ float lds_pst[8][4];

    const int tid = threadIdx.x;
    const int b = blockIdx.x;
    const int kc = tid & 3;        // k-chunk (128 k each)
    const int rg = tid >> 2;       // row group (4 rows each)
    const int r_out = tid;         // this thread's output row

    // ---------------- init: load weights (f32 source) as f16 pairs ----------------
    // thread: rows 4rg..4rg+3, k in [kc*128, kc*128+128) = 64 pairs/row.
    // pairs 0..47 of each row in regs (192 uints), pairs 48..63 in LDS (64 uints).
    unsigned int wreg[192];
#pragma unroll
    for (int i = 0; i < 4; ++i) {
        const int r = (rg << 2) + i;
        const float4* src = (const float4*)(g_Wrec + r * 512 + kc * 128);
#pragma unroll
        for (int g = 0; g < 16; ++g) {
            float4 f0 = src[2 * g];
            float4 f1 = src[2 * g + 1];
            unsigned int u0 = pk2_rne(f0.x, f0.y);
            unsigned int u1 = pk2_rne(f0.z, f0.w);
            unsigned int u2 = pk2_rne(f1.x, f1.y);
            unsigned int u3 = pk2_rne(f1.z, f1.w);
            if (g < 12) {
                wreg[i * 48 + g * 4 + 0] = u0;
                wreg[i * 48 + g * 4 + 1] = u1;
                wreg[i * 48 + g * 4 + 2] = u2;
                wreg[i * 48 + g * 4 + 3] = u3;
            } else {
                const int pbase = i * 16 + (g - 12) * 4;
                lds_w[pbase + 0][tid] = u0;
                lds_w[pbase + 1][tid] = u1;
                lds_w[pbase + 2][tid] = u2;
                lds_w[pbase + 3][tid] = u3;
            }
        }
    }

    float win[6];
#pragma unroll
    for (int j = 0; j < 6; ++j) win[j] = g_Win[r_out * 6 + j];
    const float bias = g_bin[r_out] + g_brec[r_out];
    const float wk0 = g_Wkey[r_out];
    const float wk1 = g_Wkey[512 + r_out];
    const float bk0 = g_bkey[0];
    const float bk1 = g_bkey[1];

    // zero both h buffers (h0 = 0)
    lds_hf[tid] = 0.0f;
    lds_hf[TDS + tid] = 0.0f;

    // tm_modified = inputs[:, 6:8, :] (f32 copy, 4 KB per batch)
    if (tid < 256) {
        const float4* s = (const float4*)(g_inputs + b * 4096 + 3072);
        float4* d = (float4*)(g_out + TM_OFF + (unsigned)b * 1024u);
        d[tid] = s[tid];
    }
    __syncthreads();

    // ---------------- sequential scan ----------------
    const float* gin = g_inputs + b * 4096;
    float key_pre = 1.0f;

    for (int t = 0; t < 512; ++t) {
        const int s = t & 7;
        if (s == 0 && t > 0) {
            __syncthreads();                       // staging writes (incl. kst) visible
            flush_window(g_out, b, tid, (t >> 3) - 1, lds_hst, lds_kst, lds_pst);
            __syncthreads();                       // flush reads done before new-window writes
        }

        float h_new = 0.0f, p0 = 0.0f, p1 = 0.0f, p2 = 0.0f, p3 = 0.0f;
        if (t > 0) {
            float x0 = gin[t];
            float x1 = gin[512 + t];
            float x2 = gin[1024 + t];
            float x3 = gin[1536 + t];
            float x4 = gin[2048 + t];
            float x5 = gin[2560 + t];
            float x6 = gin[3072 + t];
            float x7 = gin[3584 + t];
            float as0 = x2 * key_pre + x4 * (1.0f - key_pre);
            float as1 = x3 * key_pre + x5 * (1.0f - key_pre);
            float wd = bias;
            wd = fmaf(x0, win[0], wd);
            wd = fmaf(x1, win[1], wd);
            wd = fmaf(as0, win[2], wd);
            wd = fmaf(as1, win[3], wd);
            wd = fmaf(x6, win[4], wd);
            wd = fmaf(x7, win[5], wd);
            {
                float q0 = (x6 - x0) / (0.15f * x0);
                float q1 = (x6 - x1) / (0.15f * x1);
                float q2 = (x7 - as0) / (0.15f * as0);
                float q3 = (x7 - as1) / (0.15f * as1);
                p0 = q0 * q0; p1 = q1 * q1; p2 = q2 * q2; p3 = q3 * q3;
                if (x6 == 0.0f) { p0 = 0.0f; p1 = 0.0f; }
                if (x7 == 0.0f) { p2 = 0.0f; p3 = 0.0f; }
            }
            // matvec: rows 4rg..4rg+3, k-chunk kc — f32 h, f16-pair weights
            const float* hb = lds_hf + ((t - 1) & 1) * TDS + kc * 128;
            float a[4] = {0.0f, 0.0f, 0.0f, 0.0f};
            // register tier: pairs 0..47 per row (h floats 0..95)
#pragma unroll
            for (int c = 0; c < 24; ++c) {            // c-th float4 = pairs 2c, 2c+1
                float4 h4 = *(const float4*)(hb + 4 * c);
#pragma unroll
                for (int i = 0; i < 4; ++i) {
                    unsigned int u0 = wreg[i * 48 + 2 * c];
                    unsigned int u1 = wreg[i * 48 + 2 * c + 1];
                    a[i] = fmaf(flo(u0), h4.x, a[i]);
                    a[i] = fmaf(fhi(u0), h4.y, a[i]);
                    a[i] = fmaf(flo(u1), h4.z, a[i]);
                    a[i] = fmaf(fhi(u1), h4.w, a[i]);
                }
            }
            // LDS tier: pairs 48..63 per row (h floats 96..127)
#pragma unroll
            for (int c = 24; c < 32; ++c) {
                float4 h4 = *(const float4*)(hb + 4 * c);
#pragma unroll
                for (int i = 0; i < 4; ++i) {
                    unsigned int u0 = lds_w[i * 16 + (2 * c - 48)][tid];
                    unsigned int u1 = lds_w[i * 16 + (2 * c - 47)][tid];
                    a[i] = fmaf(flo(u0), h4.x, a[i]);
                    a[i] = fmaf(fhi(u0), h4.y, a[i]);
                    a[i] = fmaf(flo(u1), h4.z, a[i]);
                    a[i] = fmaf(fhi(u1), h4.w, a[i]);
                }
            }
            // reduce over the 4 k-chunks (lanes kc=0..3 adjacent in-wave)
#pragma unroll
            for (int i = 0; i < 4; ++i) {
                a[i] += __shfl_xor(a[i], 1, 64);
                a[i] += __shfl_xor(a[i], 2, 64);
            }
            float rsum = a[0];
            if (kc == 1) rsum = a[1];
            if (kc == 2) rsum = a[2];
            if (kc == 3) rsum = a[3];
            h_new = tanhf(rsum + wd);

            // write h (f32) into next buffer
            lds_hf[(t & 1) * TDS + r_out] = h_new;

            // key partial sums (wave butterfly), lane0 of each wave -> LDS
            float kp0 = h_new * wk0, kp1 = h_new * wk1;
#pragma unroll
            for (int m = 1; m < 64; m <<= 1) {
                kp0 += __shfl_xor(kp0, m, 64);
                kp1 += __shfl_xor(kp1, m, 64);
            }
            if ((tid & 63) == 0) {
                lds_ksum[t & 1][(tid >> 6) * 2 + 0] = kp0;
                lds_ksum[t & 1][(tid >> 6) * 2 + 1] = kp1;
            }
            if (tid == 0) {
                lds_pst[s][0] = p0; lds_pst[s][1] = p1;
                lds_pst[s][2] = p2; lds_pst[s][3] = p3;
            }
        } else {
            if (tid == 0) {
                lds_pst[s][0] = 0.0f; lds_pst[s][1] = 0.0f;
                lds_pst[s][2] = 0.0f; lds_pst[s][3] = 0.0f;
            }
        }
        lds_hst[s * TDS + r_out] = h_new;   // t=0 stages zeros

        __syncthreads();  // h buffer + ksum + staging visible

        float k0 = 0.0f, k1 = 0.0f;
        if (t > 0) {
            float s0 = 0.0f, s1 = 0.0f;
#pragma unroll
            for (int w = 0; w < 8; ++w) {
                s0 += lds_ksum[t & 1][w * 2 + 0];
                s1 += lds_ksum[t & 1][w * 2 + 1];
            }
            k0 = 1.0f / (1.0f + expf(-(s0 + bk0)));
            k1 = 1.0f / (1.0f + expf(-(s1 + bk1)));
            key_pre = k0;
        }
        if (tid == 0) { lds_kst[s][0] = k0; lds_kst[s][1] = k1; }
    }

    __syncthreads();
    flush_window(g_out, b, tid, 63, lds_hst, lds_kst, lds_pst);
}

extern "C" void kernel_launch(void* const* d_in, const int* in_sizes, int n_in,
                              void* d_out, int out_size, void* d_ws, size_t ws_size,
                              hipStream_t stream) {
    rnn_att_kernel<<<dim3(NBATCH), dim3(TDS), 0, stream>>>(
        (const float*)d_in[0],
        (const float*)d_in[1],
        (const float*)d_in[2],
        (const float*)d_in[3],
        (const float*)d_in[4],
        (const float*)d_in[5],
        (const float*)d_in[6],
        (float*)d_out);
}